// Round 1
// baseline (2790.341 us; speedup 1.0000x reference)
//
#include <hip/hip_runtime.h>

// ---------------- kernels ----------------

__global__ void k_deg_init(float* deg, int n) {
    int i = blockIdx.x * blockDim.x + threadIdx.x;
    if (i < n) deg[i] = 1.0f;  // self-loop
}

__global__ void k_deg_scatter(const int* __restrict__ ei, float* deg, int E, int n) {
    int e = blockIdx.x * blockDim.x + threadIdx.x;
    if (e < E) {
        int d = ei[E + e];  // dst
        if ((unsigned)d < (unsigned)n) atomicAdd(&deg[d], 1.0f);
    }
}

__global__ void k_dinv(float* deg, int n) {
    int i = blockIdx.x * blockDim.x + threadIdx.x;
    if (i < n) deg[i] = 1.0f / sqrtf(deg[i]);  // in-place: deg -> dinv
}

// y[i,f] = (x[i,0]*W1[0,f] + x[i,1]*W1[1,f]) * dinv[i];  acc = y (self-loop init)
__global__ void k_prep1(const float* __restrict__ x, const float* __restrict__ W1,
                        const float* __restrict__ dinv, float* __restrict__ y,
                        float* __restrict__ acc, int n) {
    int t = blockIdx.x * blockDim.x + threadIdx.x;
    if (t < n * 32) {
        int i = t >> 5, f = t & 31;
        float v = (x[2 * i] * W1[f] + x[2 * i + 1] * W1[32 + f]) * dinv[i];
        y[t] = v;
        acc[t] = v;
    }
}

// 8 threads per edge, float4 each: acc[d,:] += y[s,:]
__global__ void k_scatter(const int* __restrict__ ei, const float4* __restrict__ y4,
                          float* acc, int E, int n) {
    int t = blockIdx.x * blockDim.x + threadIdx.x;
    int e = t >> 3, q = t & 7;
    if (e < E) {
        int s = ei[e];
        int d = ei[E + e];
        if ((unsigned)s < (unsigned)n && (unsigned)d < (unsigned)n) {
            float4 v = y4[(size_t)s * 8 + q];
            float* p = acc + (size_t)d * 32 + q * 4;
            atomicAdd(p + 0, v.x);
            atomicAdd(p + 1, v.y);
            atomicAdd(p + 2, v.z);
            atomicAdd(p + 3, v.w);
        }
    }
}

// h1 = relu(dinv*acc + b1); y2 = (h1 @ W2) * dinv; acc2 = y2
// acc_in may alias acc_out (per-location single reader-then-writer).
__global__ void k_mid(const float* acc_in, const float* __restrict__ dinv,
                      const float* __restrict__ b1, const float* __restrict__ W2,
                      float* y_out, float* acc_out, int n) {
    __shared__ float sW[1024];
    __shared__ float sh[8][33];
    int tid = threadIdx.x;
    for (int k = tid; k < 1024; k += 256) sW[k] = W2[k];
    int ln = tid >> 5, f = tid & 31;
    int i = blockIdx.x * 8 + ln;
    float h = 0.f;
    float di = 0.f;
    if (i < n) {
        di = dinv[i];
        h = di * acc_in[(size_t)i * 32 + f] + b1[f];
        h = h > 0.f ? h : 0.f;
    }
    sh[ln][f] = h;
    __syncthreads();
    if (i < n) {
        float a = 0.f;
#pragma unroll
        for (int k = 0; k < 32; ++k) a += sh[ln][k] * sW[k * 32 + f];
        a *= di;
        y_out[(size_t)i * 32 + f] = a;
        acc_out[(size_t)i * 32 + f] = a;
    }
}

// h2 = relu(dinv*acc + b2); h3 = relu(h2 @ Wf1 + bf1); out = h3 . Wf2 + bf2
__global__ void k_final(const float* acc_in, const float* __restrict__ dinv,
                        const float* __restrict__ b2, const float* __restrict__ Wf1,
                        const float* __restrict__ bf1, const float* __restrict__ Wf2,
                        const float* __restrict__ bf2, float* __restrict__ out, int n) {
    __shared__ float sW[1024];
    __shared__ float sh[8][33];
    int tid = threadIdx.x;
    for (int k = tid; k < 1024; k += 256) sW[k] = Wf1[k];
    int ln = tid >> 5, f = tid & 31;
    int i = blockIdx.x * 8 + ln;
    float h = 0.f;
    if (i < n) {
        h = dinv[i] * acc_in[(size_t)i * 32 + f] + b2[f];
        h = h > 0.f ? h : 0.f;
    }
    sh[ln][f] = h;
    __syncthreads();
    float p = 0.f;
    if (i < n) {
        float a = bf1[f];
#pragma unroll
        for (int k = 0; k < 32; ++k) a += sh[ln][k] * sW[k * 32 + f];
        a = a > 0.f ? a : 0.f;
        p = a * Wf2[f];
    }
#pragma unroll
    for (int m = 16; m >= 1; m >>= 1) p += __shfl_xor(p, m, 64);
    if (f == 0 && i < n) out[i] = p + bf2[0];
}

// ---------------- launch ----------------

extern "C" void kernel_launch(void* const* d_in, const int* in_sizes, int n_in,
                              void* d_out, int out_size, void* d_ws, size_t ws_size,
                              hipStream_t stream) {
    const float* x   = (const float*)d_in[0];
    const int*   ei  = (const int*)d_in[1];   // [2, E] (harness canonicalizes ints to int32)
    const float* W1  = (const float*)d_in[2];
    const float* b1  = (const float*)d_in[3];
    const float* W2  = (const float*)d_in[4];
    const float* b2  = (const float*)d_in[5];
    const float* Wf1 = (const float*)d_in[6];
    const float* bf1 = (const float*)d_in[7];
    const float* Wf2 = (const float*)d_in[8];
    const float* bf2 = (const float*)d_in[9];
    float* out = (float*)d_out;

    int n = in_sizes[0] / 2;   // x is [N,2]
    int E = in_sizes[1] / 2;   // edge_index is [2,E]

    float* ws  = (float*)d_ws;
    float* deg = ws;                      // n floats (becomes dinv in place)
    float* y   = ws + n;                  // n*32
    float* acc = y + (size_t)n * 32;      // n*32

    const int B = 256;

    k_deg_init<<<(n + B - 1) / B, B, 0, stream>>>(deg, n);
    k_deg_scatter<<<(E + B - 1) / B, B, 0, stream>>>(ei, deg, E, n);
    k_dinv<<<(n + B - 1) / B, B, 0, stream>>>(deg, n);

    // conv1
    k_prep1<<<((size_t)n * 32 + B - 1) / B, B, 0, stream>>>(x, W1, deg, y, acc, n);
    k_scatter<<<((size_t)E * 8 + B - 1) / B, B, 0, stream>>>(ei, (const float4*)y, acc, E, n);

    // conv1 finalize + conv2 prep (reuse y/acc in place)
    k_mid<<<(n + 7) / 8, B, 0, stream>>>(acc, deg, b1, W2, y, acc, n);
    // conv2
    k_scatter<<<((size_t)E * 8 + B - 1) / B, B, 0, stream>>>(ei, (const float4*)y, acc, E, n);

    // conv2 finalize + MLP head
    k_final<<<(n + 7) / 8, B, 0, stream>>>(acc, deg, b2, Wf1, bf1, Wf2, bf2, out, n);
}

// Round 2
// 636.762 us; speedup vs baseline: 4.3821x; 4.3821x over previous
//
#include <hip/hip_runtime.h>

// ---------------- CSR build ----------------

__global__ void k_zero(int* counts, int n) {
    int i = blockIdx.x * blockDim.x + threadIdx.x;
    if (i < n) counts[i] = 0;
}

__global__ void k_hist(const int* __restrict__ ei, int* counts, int E, int n) {
    int e = blockIdx.x * blockDim.x + threadIdx.x;
    if (e < E) {
        int d = ei[E + e];  // dst
        if ((unsigned)d < (unsigned)n) atomicAdd(&counts[d], 1);
    }
}

// block-level inclusive scan (1024/block), block totals to bsums
__global__ void k_scan1(const int* __restrict__ counts, int* tmp, int* bsums, int n) {
    __shared__ int s[1024];
    int t = threadIdx.x;
    int i = blockIdx.x * 1024 + t;
    int v = (i < n) ? counts[i] : 0;
    s[t] = v;
    __syncthreads();
    for (int off = 1; off < 1024; off <<= 1) {
        int add = (t >= off) ? s[t - off] : 0;
        __syncthreads();
        s[t] += add;
        __syncthreads();
    }
    if (i < n) tmp[i] = s[t];
    if (t == 1023) bsums[blockIdx.x] = s[1023];
}

// scan of block sums (single block; nb <= 1024)
__global__ void k_scan2(const int* __restrict__ bsums, int* bofs, int nb) {
    __shared__ int s[1024];
    int t = threadIdx.x;
    int v = (t < nb) ? bsums[t] : 0;
    s[t] = v;
    __syncthreads();
    for (int off = 1; off < 1024; off <<= 1) {
        int add = (t >= off) ? s[t - off] : 0;
        __syncthreads();
        s[t] += add;
        __syncthreads();
    }
    if (t < nb) bofs[t] = s[t] - v;  // exclusive block offset
}

// rowStart (exclusive), cursor init, dinv = rsqrt(1+deg)
__global__ void k_scan3(const int* __restrict__ counts, const int* __restrict__ tmp,
                        const int* __restrict__ bofs, int* rowStart, int* cursor,
                        float* dinv, int n) {
    int i = blockIdx.x * blockDim.x + threadIdx.x;
    if (i < n) {
        int b = i >> 10;
        int incl = tmp[i] + bofs[b];
        int c = counts[i];
        int excl = incl - c;
        rowStart[i] = excl;
        cursor[i] = excl;
        dinv[i] = rsqrtf(1.0f + (float)c);
        if (i == n - 1) rowStart[n] = incl;  // total valid edges
    }
}

__global__ void k_fill(const int* __restrict__ ei, int* cursor, int* srclist, int E, int n) {
    int e = blockIdx.x * blockDim.x + threadIdx.x;
    if (e < E) {
        int s = ei[e];
        int d = ei[E + e];
        if ((unsigned)s < (unsigned)n && (unsigned)d < (unsigned)n) {
            int pos = atomicAdd(&cursor[d], 1);
            srclist[pos] = s;
        }
    }
}

// ---------------- GCN compute ----------------

// y[i,f] = (x[i,0]*W1[0,f] + x[i,1]*W1[1,f]) * dinv[i]
__global__ void k_prep1(const float* __restrict__ x, const float* __restrict__ W1,
                        const float* __restrict__ dinv, float* __restrict__ y, int n) {
    int t = blockIdx.x * blockDim.x + threadIdx.x;
    if (t < n * 32) {
        int i = t >> 5, f = t & 31;
        y[t] = (x[2 * i] * W1[f] + x[2 * i + 1] * W1[32 + f]) * dinv[i];
    }
}

// one wave per node: acc[i,:] = y[i,:] + sum_{s in in-edges(i)} y[s,:]
__global__ void k_gather(const int* __restrict__ rowStart, const int* __restrict__ srclist,
                         const float4* __restrict__ y4, float4* __restrict__ acc4, int n) {
    int w = blockIdx.x * (blockDim.x >> 6) + (threadIdx.x >> 6);
    if (w >= n) return;
    int lane = threadIdx.x & 63;
    int slot = lane >> 3, q = lane & 7;
    int start = rowStart[w], end = rowStart[w + 1];
    float4 a = make_float4(0.f, 0.f, 0.f, 0.f);
    for (int e = start + slot; e < end; e += 8) {
        int s = srclist[e];
        if ((unsigned)s < (unsigned)n) {
            float4 v = y4[(size_t)s * 8 + q];
            a.x += v.x; a.y += v.y; a.z += v.z; a.w += v.w;
        }
    }
#pragma unroll
    for (int m = 8; m < 64; m <<= 1) {
        a.x += __shfl_xor(a.x, m, 64);
        a.y += __shfl_xor(a.y, m, 64);
        a.z += __shfl_xor(a.z, m, 64);
        a.w += __shfl_xor(a.w, m, 64);
    }
    if (slot == 0) {
        float4 v = y4[(size_t)w * 8 + q];  // self-loop
        a.x += v.x; a.y += v.y; a.z += v.z; a.w += v.w;
        acc4[(size_t)w * 8 + q] = a;
    }
}

// h1 = relu(dinv*acc + b1); y2 = (h1 @ W2) * dinv
__global__ void k_mid(const float* __restrict__ acc, const float* __restrict__ dinv,
                      const float* __restrict__ b1, const float* __restrict__ W2,
                      float* __restrict__ y_out, int n) {
    __shared__ float sW[1024];
    __shared__ float sh[8][33];
    int tid = threadIdx.x;
    for (int k = tid; k < 1024; k += 256) sW[k] = W2[k];
    int ln = tid >> 5, f = tid & 31;
    int i = blockIdx.x * 8 + ln;
    float h = 0.f, di = 0.f;
    if (i < n) {
        di = dinv[i];
        h = di * acc[(size_t)i * 32 + f] + b1[f];
        h = h > 0.f ? h : 0.f;
    }
    sh[ln][f] = h;
    __syncthreads();
    if (i < n) {
        float a = 0.f;
#pragma unroll
        for (int k = 0; k < 32; ++k) a += sh[ln][k] * sW[k * 32 + f];
        y_out[(size_t)i * 32 + f] = a * di;
    }
}

// h2 = relu(dinv*acc + b2); h3 = relu(h2 @ Wf1 + bf1); out = h3 . Wf2 + bf2
__global__ void k_final(const float* __restrict__ acc, const float* __restrict__ dinv,
                        const float* __restrict__ b2, const float* __restrict__ Wf1,
                        const float* __restrict__ bf1, const float* __restrict__ Wf2,
                        const float* __restrict__ bf2, float* __restrict__ out, int n) {
    __shared__ float sW[1024];
    __shared__ float sh[8][33];
    int tid = threadIdx.x;
    for (int k = tid; k < 1024; k += 256) sW[k] = Wf1[k];
    int ln = tid >> 5, f = tid & 31;
    int i = blockIdx.x * 8 + ln;
    float h = 0.f;
    if (i < n) {
        h = dinv[i] * acc[(size_t)i * 32 + f] + b2[f];
        h = h > 0.f ? h : 0.f;
    }
    sh[ln][f] = h;
    __syncthreads();
    float p = 0.f;
    if (i < n) {
        float a = bf1[f];
#pragma unroll
        for (int k = 0; k < 32; ++k) a += sh[ln][k] * sW[k * 32 + f];
        a = a > 0.f ? a : 0.f;
        p = a * Wf2[f];
    }
#pragma unroll
    for (int m = 16; m >= 1; m >>= 1) p += __shfl_xor(p, m, 64);
    if (f == 0 && i < n) out[i] = p + bf2[0];
}

// ---------------- launch ----------------

extern "C" void kernel_launch(void* const* d_in, const int* in_sizes, int n_in,
                              void* d_out, int out_size, void* d_ws, size_t ws_size,
                              hipStream_t stream) {
    const float* x   = (const float*)d_in[0];
    const int*   ei  = (const int*)d_in[1];
    const float* W1  = (const float*)d_in[2];
    const float* b1  = (const float*)d_in[3];
    const float* W2  = (const float*)d_in[4];
    const float* b2  = (const float*)d_in[5];
    const float* Wf1 = (const float*)d_in[6];
    const float* bf1 = (const float*)d_in[7];
    const float* Wf2 = (const float*)d_in[8];
    const float* bf2 = (const float*)d_in[9];
    float* out = (float*)d_out;

    int n = in_sizes[0] / 2;   // x is [N,2]
    int E = in_sizes[1] / 2;   // edge_index is [2,E]

    // workspace layout (all chunks 16B-aligned)
    int* srclist  = (int*)d_ws;                 // E
    int* rowStart = srclist + E;                // n+4 (padded)
    int* counts   = rowStart + (n + 4);         // n
    int* cursor   = counts + n;                 // n
    int* tmp      = cursor + n;                 // n
    int* bsums    = tmp + n;                    // 1024
    int* bofs     = bsums + 1024;               // 1024
    float* dinv   = (float*)(bofs + 1024);      // n
    float* y      = dinv + n;                   // 32n
    float* acc    = y + (size_t)n * 32;         // 32n

    const int B = 256;
    int nb = (n + 1023) / 1024;

    // CSR build
    k_zero<<<(n + B - 1) / B, B, 0, stream>>>(counts, n);
    k_hist<<<(E + B - 1) / B, B, 0, stream>>>(ei, counts, E, n);
    k_scan1<<<nb, 1024, 0, stream>>>(counts, tmp, bsums, n);
    k_scan2<<<1, 1024, 0, stream>>>(bsums, bofs, nb);
    k_scan3<<<(n + B - 1) / B, B, 0, stream>>>(counts, tmp, bofs, rowStart, cursor, dinv, n);
    k_fill<<<(E + B - 1) / B, B, 0, stream>>>(ei, cursor, srclist, E, n);

    // conv1
    k_prep1<<<((size_t)n * 32 + B - 1) / B, B, 0, stream>>>(x, W1, dinv, y, n);
    k_gather<<<(n + 3) / 4, B, 0, stream>>>(rowStart, srclist, (const float4*)y, (float4*)acc, n);

    // conv1 finalize + conv2 prep
    k_mid<<<(n + 7) / 8, B, 0, stream>>>(acc, dinv, b1, W2, y, n);
    // conv2
    k_gather<<<(n + 3) / 4, B, 0, stream>>>(rowStart, srclist, (const float4*)y, (float4*)acc, n);

    // conv2 finalize + MLP head
    k_final<<<(n + 7) / 8, B, 0, stream>>>(acc, dinv, b2, Wf1, bf1, Wf2, bf2, out, n);
}